// Round 4
// baseline (914.590 us; speedup 1.0000x reference)
//
#include <hip/hip_runtime.h>
#include <hip/hip_fp16.h>

// ---------------- problem constants ----------------
constexpr int   NN   = 100000;      // nodes
constexpr int   NE   = 3200000;     // edges
constexpr int   RS   = 96;          // padded CSR row stride (P(deg>=96) ~ e^-41)
constexpr float BN_EPS = 1e-5f;

// ============================================================
// One-pass padded CSR build: slot from returning atomic.
// cursor must be zeroed before this kernel.
// ============================================================
__global__ __launch_bounds__(256) void k_fill(const int* __restrict__ ei,
                                              int* __restrict__ cursor,
                                              int* __restrict__ csrc) {
  int e = blockIdx.x * 256 + threadIdx.x;
  if (e >= NE) return;
  int s = ei[e];            // edge_index[0] = src
  int d = ei[NE + e];       // edge_index[1] = dst
  int old = atomicAdd(&cursor[d], 1);
  if (old < RS) csrc[d * RS + old] = s;   // overflow astronomically unlikely; dropped
}

__global__ __launch_bounds__(256) void k_dinv(const int* __restrict__ deg,
                                              float* __restrict__ dinv) {
  int i = blockIdx.x * 256 + threadIdx.x;
  if (i < NN) dinv[i] = rsqrtf((float)(deg[i] + 1));   // +1 self-loop
}

// ============================================================
// fp32 GEMM -> fp16 gather table:
// Ht[r,:] = fp16( dinv[r] * ( act(A[r,:]) @ W ) ), BN_ cols
// act = identity (layer 1) or fused BatchNorm+ReLU (layers 2,3).
// Block: 64 rows x BN_ cols, BK=32, 256 threads, 4x(4*NG) micro-tile.
// ============================================================
template <int BN_, bool FUSE_BN>
__global__ __launch_bounds__(256) void k_gemm(const float* __restrict__ A,
                                              const float* __restrict__ W,
                                              const float* __restrict__ scale,
                                              const float* __restrict__ shift,
                                              const float* __restrict__ dinv,
                                              __half* __restrict__ C) {
  constexpr int NG = BN_ / 64;        // col groups per thread (2 for 128, 1 for 64)
  constexpr int AS = 36;              // padded LDS stride for A tile
  __shared__ __align__(16) float As[64 * AS];
  __shared__ __align__(16) float Bs[32 * BN_];
  __shared__ __align__(16) float sc[128];
  __shared__ __align__(16) float sh[128];

  const int t = threadIdx.x;
  if (FUSE_BN) {
    if (t < 128) { sc[t] = scale[t]; sh[t] = shift[t]; }
    __syncthreads();
  }

  const int row0 = blockIdx.x * 64;
  const int trow = t >> 4;            // 0..15
  const int tcol = t & 15;            // 0..15

  float acc[4][NG * 4];
#pragma unroll
  for (int i = 0; i < 4; ++i)
#pragma unroll
    for (int j = 0; j < NG * 4; ++j) acc[i][j] = 0.f;

  for (int kt = 0; kt < 4; ++kt) {
    // ---- A tile: 64x32, 2 float4 per thread ----
#pragma unroll
    for (int i = 0; i < 2; ++i) {
      int fid = t + i * 256;
      int r   = fid >> 3;             // 0..63
      int c4  = fid & 7;              // 0..7
      int row = row0 + r;
      float4 v = make_float4(0.f, 0.f, 0.f, 0.f);
      if (row < NN)
        v = *(const float4*)(A + (size_t)row * 128 + kt * 32 + c4 * 4);
      if (FUSE_BN) {
        int k = kt * 32 + c4 * 4;
        float4 s4 = *(const float4*)&sc[k];
        float4 h4 = *(const float4*)&sh[k];
        v.x = fmaxf(v.x * s4.x + h4.x, 0.f);
        v.y = fmaxf(v.y * s4.y + h4.y, 0.f);
        v.z = fmaxf(v.z * s4.z + h4.z, 0.f);
        v.w = fmaxf(v.w * s4.w + h4.w, 0.f);
      }
      *(float4*)&As[r * AS + c4 * 4] = v;
    }
    // ---- B tile: 32 x BN_ ----
    constexpr int NB = (32 * BN_) / 4 / 256;
#pragma unroll
    for (int i = 0; i < NB; ++i) {
      int fid = t + i * 256;
      int r   = fid / (BN_ / 4);
      int c4  = fid % (BN_ / 4);
      *(float4*)&Bs[r * BN_ + c4 * 4] =
          *(const float4*)(W + (size_t)(kt * 32 + r) * BN_ + c4 * 4);
    }
    __syncthreads();

#pragma unroll 8
    for (int k = 0; k < 32; ++k) {
      float a0 = As[(4 * trow + 0) * AS + k];
      float a1 = As[(4 * trow + 1) * AS + k];
      float a2 = As[(4 * trow + 2) * AS + k];
      float a3 = As[(4 * trow + 3) * AS + k];
#pragma unroll
      for (int g = 0; g < NG; ++g) {
        float4 b = *(const float4*)&Bs[k * BN_ + g * 64 + tcol * 4];
        acc[0][g*4+0] += a0 * b.x; acc[0][g*4+1] += a0 * b.y;
        acc[0][g*4+2] += a0 * b.z; acc[0][g*4+3] += a0 * b.w;
        acc[1][g*4+0] += a1 * b.x; acc[1][g*4+1] += a1 * b.y;
        acc[1][g*4+2] += a1 * b.z; acc[1][g*4+3] += a1 * b.w;
        acc[2][g*4+0] += a2 * b.x; acc[2][g*4+1] += a2 * b.y;
        acc[2][g*4+2] += a2 * b.z; acc[2][g*4+3] += a2 * b.w;
        acc[3][g*4+0] += a3 * b.x; acc[3][g*4+1] += a3 * b.y;
        acc[3][g*4+2] += a3 * b.z; acc[3][g*4+3] += a3 * b.w;
      }
    }
    __syncthreads();
  }

#pragma unroll
  for (int i = 0; i < 4; ++i) {
    int row = row0 + 4 * trow + i;
    if (row < NN) {
      float dv = dinv[row];           // fold deg^-1/2 of the SOURCE into Ht
#pragma unroll
      for (int g = 0; g < NG; ++g) {
        union { __half2 h[2]; uint2 u; } pk;
        pk.h[0] = __floats2half2_rn(acc[i][g*4+0] * dv, acc[i][g*4+1] * dv);
        pk.h[1] = __floats2half2_rn(acc[i][g*4+2] * dv, acc[i][g*4+3] * dv);
        *(uint2*)(C + (size_t)row * BN_ + g * 64 + tcol * 4) = pk.u;
      }
    }
  }
}

// ============================================================
// Pull aggregation, D=128 fp16 table -> fp32 out, padded CSR:
// out[i] = dinv_i * (Ht[i] + sum_j Ht[s_j]); one wave per node,
// lane holds one __half2 (row = 256 B = 64 lanes x 4 B).
// ============================================================
__global__ __launch_bounds__(256) void k_agg128(const __half* __restrict__ H,
                                                const float* __restrict__ dinv,
                                                const int* __restrict__ deg,
                                                const int* __restrict__ csrc,
                                                float* __restrict__ out) {
  int wid  = (blockIdx.x * 256 + threadIdx.x) >> 6;
  int lane = threadIdx.x & 63;
  if (wid >= NN) return;
  const __half2* Hp = (const __half2*)H;
  float2 acc = __half22float2(Hp[(size_t)wid * 64 + lane]);   // self term
  const int* srcs = csrc + (size_t)wid * RS;
  int cnt = min(deg[wid], RS);
  int e = 0;
  int end8 = cnt & ~7;
  for (; e < end8; e += 8) {
    __half2 v0 = Hp[(size_t)srcs[e+0] * 64 + lane];
    __half2 v1 = Hp[(size_t)srcs[e+1] * 64 + lane];
    __half2 v2 = Hp[(size_t)srcs[e+2] * 64 + lane];
    __half2 v3 = Hp[(size_t)srcs[e+3] * 64 + lane];
    __half2 v4 = Hp[(size_t)srcs[e+4] * 64 + lane];
    __half2 v5 = Hp[(size_t)srcs[e+5] * 64 + lane];
    __half2 v6 = Hp[(size_t)srcs[e+6] * 64 + lane];
    __half2 v7 = Hp[(size_t)srcs[e+7] * 64 + lane];
    float2 f0 = __half22float2(v0), f1 = __half22float2(v1);
    float2 f2 = __half22float2(v2), f3 = __half22float2(v3);
    float2 f4 = __half22float2(v4), f5 = __half22float2(v5);
    float2 f6 = __half22float2(v6), f7 = __half22float2(v7);
    acc.x += (f0.x + f1.x) + (f2.x + f3.x) + (f4.x + f5.x) + (f6.x + f7.x);
    acc.y += (f0.y + f1.y) + (f2.y + f3.y) + (f4.y + f5.y) + (f6.y + f7.y);
  }
  for (; e < cnt; ++e) {
    float2 f = __half22float2(Hp[(size_t)srcs[e] * 64 + lane]);
    acc.x += f.x; acc.y += f.y;
  }
  float di = dinv[wid];
  acc.x *= di; acc.y *= di;
  ((float2*)out)[(size_t)wid * 64 + lane] = acc;
}

// ============================================================
// Final layer: aggregation (D=64, fp16 table) + bias + softmax
// ============================================================
__global__ __launch_bounds__(256) void k_agg64_softmax(const __half* __restrict__ H,
                                                       const float* __restrict__ dinv,
                                                       const int* __restrict__ deg,
                                                       const int* __restrict__ csrc,
                                                       const float* __restrict__ b3,
                                                       float* __restrict__ out) {
  int wid  = (blockIdx.x * 256 + threadIdx.x) >> 6;
  int lane = threadIdx.x & 63;
  if (wid >= NN) return;
  float acc = __half2float(H[(size_t)wid * 64 + lane]);   // self term
  const int* srcs = csrc + (size_t)wid * RS;
  int cnt = min(deg[wid], RS);
  int e = 0;
  int end8 = cnt & ~7;
  for (; e < end8; e += 8) {
    float v0 = __half2float(H[(size_t)srcs[e+0] * 64 + lane]);
    float v1 = __half2float(H[(size_t)srcs[e+1] * 64 + lane]);
    float v2 = __half2float(H[(size_t)srcs[e+2] * 64 + lane]);
    float v3 = __half2float(H[(size_t)srcs[e+3] * 64 + lane]);
    float v4 = __half2float(H[(size_t)srcs[e+4] * 64 + lane]);
    float v5 = __half2float(H[(size_t)srcs[e+5] * 64 + lane]);
    float v6 = __half2float(H[(size_t)srcs[e+6] * 64 + lane]);
    float v7 = __half2float(H[(size_t)srcs[e+7] * 64 + lane]);
    acc += (v0 + v1) + (v2 + v3) + (v4 + v5) + (v6 + v7);
  }
  for (; e < cnt; ++e)
    acc += __half2float(H[(size_t)srcs[e] * 64 + lane]);
  acc = acc * dinv[wid] + b3[lane];

  // softmax across the 64 lanes
  float m = acc;
#pragma unroll
  for (int off = 32; off > 0; off >>= 1) m = fmaxf(m, __shfl_xor(m, off));
  float ev = __expf(acc - m);
  float s = ev;
#pragma unroll
  for (int off = 32; off > 0; off >>= 1) s += __shfl_xor(s, off);
  out[(size_t)wid * 64 + lane] = ev / s;
}

// ============================================================
// BatchNorm column stats (sum, sum of squares) over fp32 agg out
// ============================================================
__global__ __launch_bounds__(256) void k_stats(const float* __restrict__ H,
                                               float* __restrict__ S1,
                                               float* __restrict__ S2) {
  int t = threadIdx.x;
  int col  = t & 127;
  int half = t >> 7;
  float s1 = 0.f, s2 = 0.f;
  for (int row = blockIdx.x * 2 + half; row < NN; row += gridDim.x * 2) {
    float v = H[(size_t)row * 128 + col];
    s1 += v; s2 += v * v;
  }
  __shared__ float l1[256], l2[256];
  l1[t] = s1; l2[t] = s2;
  __syncthreads();
  if (t < 128) {
    atomicAdd(&S1[col], l1[t] + l1[t + 128]);
    atomicAdd(&S2[col], l2[t] + l2[t + 128]);
  }
}

__global__ void k_finalize(const float* __restrict__ S1, const float* __restrict__ S2,
                           const float* __restrict__ g,  const float* __restrict__ be,
                           float* __restrict__ scale,    float* __restrict__ shift) {
  int t = threadIdx.x;  // 128 threads
  float mean = S1[t] * (1.0f / NN);
  float var  = S2[t] * (1.0f / NN) - mean * mean;
  float is   = rsqrtf(var + BN_EPS);
  float sc   = g[t] * is;
  scale[t] = sc;
  shift[t] = be[t] - mean * sc;
}

// ============================================================
// host launch
// ============================================================
extern "C" void kernel_launch(void* const* d_in, const int* in_sizes, int n_in,
                              void* d_out, int out_size, void* d_ws, size_t ws_size,
                              hipStream_t stream) {
  (void)in_sizes; (void)n_in; (void)out_size; (void)ws_size;
  const float* x   = (const float*)d_in[0];
  const int*   ei  = (const int*)d_in[1];
  const float* W1  = (const float*)d_in[2];
  // d_in[3] = b1: cancels in BatchNorm (constant column shift), skipped
  const float* W2  = (const float*)d_in[4];
  // d_in[5] = b2: same
  const float* W3  = (const float*)d_in[6];
  const float* b3  = (const float*)d_in[7];
  const float* g1  = (const float*)d_in[8];
  const float* be1 = (const float*)d_in[9];
  const float* g2  = (const float*)d_in[10];
  const float* be2 = (const float*)d_in[11];
  float* out = (float*)d_out;

  char* ws = (char*)d_ws;
  size_t off = 0;
  auto take = [&](size_t bytes) -> char* {
    char* p = ws + off;
    off = (off + bytes + 255) & ~(size_t)255;
    return p;
  };
  int*   cursor = (int*)  take((size_t)NN * 4);   // degree counter / padded-CSR cursor
  float* S1a    = (float*)take(128 * 4);
  float* S2a    = (float*)take(128 * 4);
  float* S1b    = (float*)take(128 * 4);
  float* S2b    = (float*)take(128 * 4);
  size_t zero_bytes = off;                  // cursor + stats zeroed each call
  float* scale1 = (float*)take(128 * 4);
  float* shift1 = (float*)take(128 * 4);
  float* scale2 = (float*)take(128 * 4);
  float* shift2 = (float*)take(128 * 4);
  float* dinv   = (float*)take((size_t)NN * 4);
  int*   csrc   = (int*)  take((size_t)NN * RS * 4);     // 38.4 MB padded CSR
  __half* Hf    = (__half*)take((size_t)NN * 128 * 2);   // fp16 gather table
  float*  bufB  = (float*) take((size_t)NN * 128 * 4);   // fp32 agg output

  (void)hipMemsetAsync(d_ws, 0, zero_bytes, stream);

  const int nbE = (NE + 255) / 256;
  const int nbN = (NN + 255) / 256;         // 391
  const int gemmB = (NN + 63) / 64;         // 1563
  const int aggB  = (NN + 3) / 4;           // 25000

  k_fill<<<nbE, 256, 0, stream>>>(ei, cursor, csrc);
  k_dinv<<<nbN, 256, 0, stream>>>(cursor, dinv);

  // layer 1
  k_gemm<128, false><<<gemmB, 256, 0, stream>>>(x, W1, nullptr, nullptr, dinv, Hf);
  k_agg128<<<aggB, 256, 0, stream>>>(Hf, dinv, cursor, csrc, bufB);
  k_stats<<<1024, 256, 0, stream>>>(bufB, S1a, S2a);
  k_finalize<<<1, 128, 0, stream>>>(S1a, S2a, g1, be1, scale1, shift1);

  // layer 2 (BN+ReLU fused into GEMM input load)
  k_gemm<128, true><<<gemmB, 256, 0, stream>>>(bufB, W2, scale1, shift1, dinv, Hf);
  k_agg128<<<aggB, 256, 0, stream>>>(Hf, dinv, cursor, csrc, bufB);
  k_stats<<<1024, 256, 0, stream>>>(bufB, S1b, S2b);
  k_finalize<<<1, 128, 0, stream>>>(S1b, S2b, g2, be2, scale2, shift2);

  // layer 3 (BN+ReLU fused) -> N x 64 fp16, then aggregation + bias + softmax
  k_gemm<64, true><<<gemmB, 256, 0, stream>>>(bufB, W3, scale2, shift2, dinv, Hf);
  k_agg64_softmax<<<aggB, 256, 0, stream>>>(Hf, dinv, cursor, csrc, b3, out);
}

// Round 5
// 842.447 us; speedup vs baseline: 1.0856x; 1.0856x over previous
//
#include <hip/hip_runtime.h>
#include <hip/hip_fp16.h>

// ---------------- problem constants ----------------
constexpr int   NN   = 100000;      // nodes
constexpr int   NE   = 3200000;     // edges
constexpr float BN_EPS = 1e-5f;

typedef _Float16 half8 __attribute__((ext_vector_type(8)));
typedef float    floatx16 __attribute__((ext_vector_type(16)));

// ============================================================
// CSR build: count(+slot) -> scan -> fill (atomic-free fill)
// ============================================================
__global__ __launch_bounds__(256) void k_count(const int* __restrict__ dst,
                                               int* __restrict__ deg,
                                               int* __restrict__ slot) {
  int e = blockIdx.x * 256 + threadIdx.x;
  if (e < NE) slot[e] = atomicAdd(&deg[dst[e]], 1);
}

__global__ __launch_bounds__(256) void k_scan_a(const int* __restrict__ deg,
                                                float* __restrict__ dinv,
                                                int* __restrict__ rowptr,
                                                int* __restrict__ bsum) {
  __shared__ int sd[256];
  int t = threadIdx.x;
  int i = blockIdx.x * 256 + t;
  int v = (i < NN) ? deg[i] : 0;
  if (i < NN) dinv[i] = rsqrtf((float)(v + 1));   // +1 self-loop
  sd[t] = v;
  __syncthreads();
  for (int off = 1; off < 256; off <<= 1) {
    int x = (t >= off) ? sd[t - off] : 0;
    __syncthreads();
    sd[t] += x;
    __syncthreads();
  }
  if (i < NN) rowptr[i] = sd[t] - v;              // exclusive
  if (t == 255) bsum[blockIdx.x] = sd[255];
}

__global__ __launch_bounds__(512) void k_scan_b(int* __restrict__ bsum, int nb) {
  __shared__ int sd[512];
  int t = threadIdx.x;
  int v = (t < nb) ? bsum[t] : 0;
  sd[t] = v;
  __syncthreads();
  for (int off = 1; off < 512; off <<= 1) {
    int x = (t >= off) ? sd[t - off] : 0;
    __syncthreads();
    sd[t] += x;
    __syncthreads();
  }
  if (t < nb) bsum[t] = sd[t] - v;                // exclusive block offsets
}

__global__ __launch_bounds__(256) void k_scan_c(int* __restrict__ rowptr,
                                                const int* __restrict__ bsum) {
  int i = blockIdx.x * 256 + threadIdx.x;
  if (i < NN) rowptr[i] += bsum[blockIdx.x];
  if (i == 0) rowptr[NN] = NE;
}

__global__ __launch_bounds__(256) void k_fill(const int* __restrict__ ei,
                                              const int* __restrict__ rowptr,
                                              const int* __restrict__ slot,
                                              int* __restrict__ csrc) {
  int e = blockIdx.x * 256 + threadIdx.x;
  if (e >= NE) return;
  int s = ei[e];            // edge_index[0] = src
  int d = ei[NE + e];       // edge_index[1] = dst
  csrc[rowptr[d] + slot[e]] = s;
}

// ============================================================
// Weight prep: Wt[n][k] = fp16(W[k][n])  (transpose + cast, tiny)
// ============================================================
template <int BN_>
__global__ __launch_bounds__(256) void k_wprep(const float* __restrict__ W,
                                               _Float16* __restrict__ Wt) {
  int idx = blockIdx.x * 256 + threadIdx.x;
  if (idx >= 128 * BN_) return;
  int k = idx / BN_, n = idx % BN_;
  Wt[n * 128 + k] = (_Float16)W[idx];
}

// ============================================================
// MFMA f16 GEMM (register-only, no LDS):
// Ht[r,:] = fp16( dinv[r] * ( act(A[r,:]) @ W ) ), K=128, BN_ cols.
// One wave = 32 rows x BN_ cols. v_mfma_f32_32x32x16_f16:
//   A-frag: A[m=lane&31][k=(lane>>5)*8+j], j=0..7 (half8)
//   B-frag: B[k=(lane>>5)*8+j][n=lane&31]  == Wt[n][k] contiguous
//   C/D:    col=lane&31, row=(reg&3)+8*(reg>>2)+4*(lane>>5)  [m74/m101]
// act = identity (layer 1) or BatchNorm+ReLU (layers 2,3) on the fp32 load.
// ============================================================
template <int BN_, bool FUSE_BN>
__global__ __launch_bounds__(256) void k_mgemm(const float* __restrict__ A,
                                               const _Float16* __restrict__ Wt,
                                               const float* __restrict__ scale,
                                               const float* __restrict__ shift,
                                               const float* __restrict__ dinv,
                                               _Float16* __restrict__ C) {
  constexpr int NCT = BN_ / 32;       // col tiles per wave
  int wid  = (blockIdx.x * 256 + threadIdx.x) >> 6;   // wave id = 32-row block
  int lane = threadIdx.x & 63;
  if (wid >= NN / 32) return;                         // 3125 waves exactly
  const int m = lane & 31;
  const int q = lane >> 5;
  const int row0 = wid * 32;

  const float* Arow = A + (size_t)(row0 + m) * 128 + q * 8;

  floatx16 acc[NCT] = {};

#pragma unroll
  for (int s = 0; s < 8; ++s) {       // K = 8 steps x 16
    float4 a0 = *(const float4*)(Arow + 16 * s);
    float4 a1 = *(const float4*)(Arow + 16 * s + 4);
    if (FUSE_BN) {
      int k0 = 16 * s + q * 8;
      float4 sc0 = *(const float4*)(scale + k0);
      float4 sc1 = *(const float4*)(scale + k0 + 4);
      float4 sh0 = *(const float4*)(shift + k0);
      float4 sh1 = *(const float4*)(shift + k0 + 4);
      a0.x = fmaxf(fmaf(a0.x, sc0.x, sh0.x), 0.f);
      a0.y = fmaxf(fmaf(a0.y, sc0.y, sh0.y), 0.f);
      a0.z = fmaxf(fmaf(a0.z, sc0.z, sh0.z), 0.f);
      a0.w = fmaxf(fmaf(a0.w, sc0.w, sh0.w), 0.f);
      a1.x = fmaxf(fmaf(a1.x, sc1.x, sh1.x), 0.f);
      a1.y = fmaxf(fmaf(a1.y, sc1.y, sh1.y), 0.f);
      a1.z = fmaxf(fmaf(a1.z, sc1.z, sh1.z), 0.f);
      a1.w = fmaxf(fmaf(a1.w, sc1.w, sh1.w), 0.f);
    }
    half8 af;
    af[0] = (_Float16)a0.x; af[1] = (_Float16)a0.y;
    af[2] = (_Float16)a0.z; af[3] = (_Float16)a0.w;
    af[4] = (_Float16)a1.x; af[5] = (_Float16)a1.y;
    af[6] = (_Float16)a1.z; af[7] = (_Float16)a1.w;
#pragma unroll
    for (int ct = 0; ct < NCT; ++ct) {
      half8 bf = *(const half8*)(Wt + (size_t)(ct * 32 + m) * 128 + q * 8 + 16 * s);
      acc[ct] = __builtin_amdgcn_mfma_f32_32x32x16_f16(af, bf, acc[ct], 0, 0, 0);
    }
  }

  // epilogue: scale rows by dinv, cast to fp16, store
#pragma unroll
  for (int ct = 0; ct < NCT; ++ct) {
#pragma unroll
    for (int r = 0; r < 16; ++r) {
      int row = (r & 3) + 8 * (r >> 2) + 4 * q;
      float dv = dinv[row0 + row];
      C[(size_t)(row0 + row) * BN_ + ct * 32 + m] = (_Float16)(acc[ct][r] * dv);
    }
  }
}

// ============================================================
// Pull aggregation, D=128 fp16 table -> fp32 out:
// out[i] = dinv_i * (Ht[i] + sum_j Ht[s_j]); one wave per node.
// ============================================================
__global__ __launch_bounds__(256) void k_agg128(const __half* __restrict__ H,
                                                const float* __restrict__ dinv,
                                                const int* __restrict__ rowptr,
                                                const int* __restrict__ srcs,
                                                float* __restrict__ out) {
  int wid  = (blockIdx.x * 256 + threadIdx.x) >> 6;
  int lane = threadIdx.x & 63;
  if (wid >= NN) return;
  const __half2* Hp = (const __half2*)H;
  float2 acc = __half22float2(Hp[(size_t)wid * 64 + lane]);   // self term
  int beg = rowptr[wid], end = rowptr[wid + 1];
  int e = beg;
  int end8 = beg + ((end - beg) & ~7);
  for (; e < end8; e += 8) {
    __half2 v0 = Hp[(size_t)srcs[e+0] * 64 + lane];
    __half2 v1 = Hp[(size_t)srcs[e+1] * 64 + lane];
    __half2 v2 = Hp[(size_t)srcs[e+2] * 64 + lane];
    __half2 v3 = Hp[(size_t)srcs[e+3] * 64 + lane];
    __half2 v4 = Hp[(size_t)srcs[e+4] * 64 + lane];
    __half2 v5 = Hp[(size_t)srcs[e+5] * 64 + lane];
    __half2 v6 = Hp[(size_t)srcs[e+6] * 64 + lane];
    __half2 v7 = Hp[(size_t)srcs[e+7] * 64 + lane];
    float2 f0 = __half22float2(v0), f1 = __half22float2(v1);
    float2 f2 = __half22float2(v2), f3 = __half22float2(v3);
    float2 f4 = __half22float2(v4), f5 = __half22float2(v5);
    float2 f6 = __half22float2(v6), f7 = __half22float2(v7);
    acc.x += (f0.x + f1.x) + (f2.x + f3.x) + (f4.x + f5.x) + (f6.x + f7.x);
    acc.y += (f0.y + f1.y) + (f2.y + f3.y) + (f4.y + f5.y) + (f6.y + f7.y);
  }
  for (; e < end; ++e) {
    float2 f = __half22float2(Hp[(size_t)srcs[e] * 64 + lane]);
    acc.x += f.x; acc.y += f.y;
  }
  float di = dinv[wid];
  acc.x *= di; acc.y *= di;
  ((float2*)out)[(size_t)wid * 64 + lane] = acc;
}

// ============================================================
// Final layer: aggregation (D=64, fp16 table) + bias + softmax
// ============================================================
__global__ __launch_bounds__(256) void k_agg64_softmax(const __half* __restrict__ H,
                                                       const float* __restrict__ dinv,
                                                       const int* __restrict__ rowptr,
                                                       const int* __restrict__ srcs,
                                                       const float* __restrict__ b3,
                                                       float* __restrict__ out) {
  int wid  = (blockIdx.x * 256 + threadIdx.x) >> 6;
  int lane = threadIdx.x & 63;
  if (wid >= NN) return;
  float acc = __half2float(H[(size_t)wid * 64 + lane]);   // self term
  int beg = rowptr[wid], end = rowptr[wid + 1];
  int e = beg;
  int end8 = beg + ((end - beg) & ~7);
  for (; e < end8; e += 8) {
    float v0 = __half2float(H[(size_t)srcs[e+0] * 64 + lane]);
    float v1 = __half2float(H[(size_t)srcs[e+1] * 64 + lane]);
    float v2 = __half2float(H[(size_t)srcs[e+2] * 64 + lane]);
    float v3 = __half2float(H[(size_t)srcs[e+3] * 64 + lane]);
    float v4 = __half2float(H[(size_t)srcs[e+4] * 64 + lane]);
    float v5 = __half2float(H[(size_t)srcs[e+5] * 64 + lane]);
    float v6 = __half2float(H[(size_t)srcs[e+6] * 64 + lane]);
    float v7 = __half2float(H[(size_t)srcs[e+7] * 64 + lane]);
    acc += (v0 + v1) + (v2 + v3) + (v4 + v5) + (v6 + v7);
  }
  for (; e < end; ++e)
    acc += __half2float(H[(size_t)srcs[e] * 64 + lane]);
  acc = acc * dinv[wid] + b3[lane];

  // softmax across the 64 lanes
  float m = acc;
#pragma unroll
  for (int off = 32; off > 0; off >>= 1) m = fmaxf(m, __shfl_xor(m, off));
  float ev = __expf(acc - m);
  float s = ev;
#pragma unroll
  for (int off = 32; off > 0; off >>= 1) s += __shfl_xor(s, off);
  out[(size_t)wid * 64 + lane] = ev / s;
}

// ============================================================
// BatchNorm column stats (sum, sum of squares) over fp32 agg out
// ============================================================
__global__ __launch_bounds__(256) void k_stats(const float* __restrict__ H,
                                               float* __restrict__ S1,
                                               float* __restrict__ S2) {
  int t = threadIdx.x;
  int col  = t & 127;
  int half = t >> 7;
  float s1 = 0.f, s2 = 0.f;
  for (int row = blockIdx.x * 2 + half; row < NN; row += gridDim.x * 2) {
    float v = H[(size_t)row * 128 + col];
    s1 += v; s2 += v * v;
  }
  __shared__ float l1[256], l2[256];
  l1[t] = s1; l2[t] = s2;
  __syncthreads();
  if (t < 128) {
    atomicAdd(&S1[col], l1[t] + l1[t + 128]);
    atomicAdd(&S2[col], l2[t] + l2[t + 128]);
  }
}

__global__ void k_finalize(const float* __restrict__ S1, const float* __restrict__ S2,
                           const float* __restrict__ g,  const float* __restrict__ be,
                           float* __restrict__ scale,    float* __restrict__ shift) {
  int t = threadIdx.x;  // 128 threads
  float mean = S1[t] * (1.0f / NN);
  float var  = S2[t] * (1.0f / NN) - mean * mean;
  float is   = rsqrtf(var + BN_EPS);
  float sc   = g[t] * is;
  scale[t] = sc;
  shift[t] = be[t] - mean * sc;
}

// ============================================================
// host launch
// ============================================================
extern "C" void kernel_launch(void* const* d_in, const int* in_sizes, int n_in,
                              void* d_out, int out_size, void* d_ws, size_t ws_size,
                              hipStream_t stream) {
  (void)in_sizes; (void)n_in; (void)out_size; (void)ws_size;
  const float* x   = (const float*)d_in[0];
  const int*   ei  = (const int*)d_in[1];
  const float* W1  = (const float*)d_in[2];
  // d_in[3] = b1: cancels in BatchNorm (constant column shift), skipped
  const float* W2  = (const float*)d_in[4];
  // d_in[5] = b2: same
  const float* W3  = (const float*)d_in[6];
  const float* b3  = (const float*)d_in[7];
  const float* g1  = (const float*)d_in[8];
  const float* be1 = (const float*)d_in[9];
  const float* g2  = (const float*)d_in[10];
  const float* be2 = (const float*)d_in[11];
  float* out = (float*)d_out;

  char* ws = (char*)d_ws;
  size_t off = 0;
  auto take = [&](size_t bytes) -> char* {
    char* p = ws + off;
    off = (off + bytes + 255) & ~(size_t)255;
    return p;
  };
  int*   deg    = (int*)  take((size_t)NN * 4);
  float* S1a    = (float*)take(128 * 4);
  float* S2a    = (float*)take(128 * 4);
  float* S1b    = (float*)take(128 * 4);
  float* S2b    = (float*)take(128 * 4);
  size_t zero_bytes = off;                  // deg + stats zeroed each call
  float* scale1 = (float*)take(128 * 4);
  float* shift1 = (float*)take(128 * 4);
  float* scale2 = (float*)take(128 * 4);
  float* shift2 = (float*)take(128 * 4);
  float* dinv   = (float*)take((size_t)NN * 4);
  int*   rowptr = (int*)  take((size_t)(NN + 1) * 4);
  int*   bsum   = (int*)  take(1024 * 4);
  int*   slot   = (int*)  take((size_t)NE * 4);
  int*   csrc   = (int*)  take((size_t)NE * 4);
  _Float16* Wt1 = (_Float16*)take((size_t)128 * 128 * 2);
  _Float16* Wt2 = (_Float16*)take((size_t)128 * 128 * 2);
  _Float16* Wt3 = (_Float16*)take((size_t)64 * 128 * 2);
  _Float16* Hf  = (_Float16*)take((size_t)NN * 128 * 2);  // fp16 gather table
  float*    bufB= (float*)   take((size_t)NN * 128 * 4);  // fp32 agg output

  (void)hipMemsetAsync(d_ws, 0, zero_bytes, stream);

  const int nbE = (NE + 255) / 256;
  const int nbN = (NN + 255) / 256;         // 391
  const int mgB = (NN / 32 + 3) / 4;        // 782 blocks (3125 waves)
  const int aggB  = (NN + 3) / 4;           // 25000

  k_count <<<nbE, 256, 0, stream>>>(ei + NE, deg, slot);
  k_scan_a<<<nbN, 256, 0, stream>>>(deg, dinv, rowptr, bsum);
  k_scan_b<<<1, 512, 0, stream>>>(bsum, nbN);
  k_scan_c<<<nbN, 256, 0, stream>>>(rowptr, bsum);
  k_fill  <<<nbE, 256, 0, stream>>>(ei, rowptr, slot, csrc);

  k_wprep<128><<<64, 256, 0, stream>>>(W1, Wt1);
  k_wprep<128><<<64, 256, 0, stream>>>(W2, Wt2);
  k_wprep<64> <<<32, 256, 0, stream>>>(W3, Wt3);

  // layer 1
  k_mgemm<128, false><<<mgB, 256, 0, stream>>>(x, Wt1, nullptr, nullptr, dinv, Hf);
  k_agg128<<<aggB, 256, 0, stream>>>((const __half*)Hf, dinv, rowptr, csrc, bufB);
  k_stats<<<1024, 256, 0, stream>>>(bufB, S1a, S2a);
  k_finalize<<<1, 128, 0, stream>>>(S1a, S2a, g1, be1, scale1, shift1);

  // layer 2 (BN+ReLU fused into GEMM A-load)
  k_mgemm<128, true><<<mgB, 256, 0, stream>>>(bufB, Wt2, scale1, shift1, dinv, Hf);
  k_agg128<<<aggB, 256, 0, stream>>>((const __half*)Hf, dinv, rowptr, csrc, bufB);
  k_stats<<<1024, 256, 0, stream>>>(bufB, S1b, S2b);
  k_finalize<<<1, 128, 0, stream>>>(S1b, S2b, g2, be2, scale2, shift2);

  // layer 3 (BN+ReLU fused) -> N x 64 fp16, then aggregation + bias + softmax
  k_mgemm<64, true><<<mgB, 256, 0, stream>>>(bufB, Wt3, scale2, shift2, dinv, Hf);
  k_agg64_softmax<<<aggB, 256, 0, stream>>>((const __half*)Hf, dinv, rowptr, csrc, b3, out);
}